// Round 5
// baseline (59.641 us; speedup 1.0000x reference)
//
#include <hip/hip_runtime.h>

// Problem constants (fixed by the reference)
constexpr int Bsz  = 512;
constexpr int Nn   = 256;   // agents
constexpr int FINc = 32;
constexpr int H1c  = 16;
constexpr int Gc   = 8;
constexpr int FOUTc= 16;
constexpr int Kc   = 3;
constexpr int ACTc = 5;

// One block per batch element. 512 threads = 8 waves -> 16 waves/CU (2 blocks/CU).
// Wave w owns S rows [32w, 32w+32); lane owns columns 4*lane..4*lane+3 (float4).
// z kept in LDS as f32 (2x b128 wave-uniform broadcast per row, no cvt chain).
// S loads: ping-pong register prefetch, 4 rows (4 KB/wave) in flight minimum.
__global__ __launch_bounds__(512, 4)
void cpn_kernel(const float* __restrict__ x,  const float* __restrict__ S,
                const float* __restrict__ W1, const float* __restrict__ b1,
                const float* __restrict__ W2, const float* __restrict__ b2,
                const float* __restrict__ Hgf,const float* __restrict__ bgf,
                const float* __restrict__ Wa, const float* __restrict__ ba,
                float* __restrict__ out)
{
    const int b    = blockIdx.x;
    const int tid  = threadIdx.x;
    const int wid  = tid >> 6;
    const int lane = tid & 63;
    const int n    = tid;            // agent index for phases A/C (tid < 256 only)

    __shared__ __align__(16) float zA[Nn][Gc];        // z0 f32 (8 KB)
    __shared__ __align__(16) float zB[Nn][Gc];        // z1 f32 (8 KB)
    __shared__ __align__(16) float zpart[4][Gc][Nn];  // merged partials (32 KB) -> 48 KB total

    // ---------------- Phase A: compress MLP (thread = agent n, tid<256) ----------------
    if (tid < Nn) {
        float xr[FINc];
        const float4* xp = reinterpret_cast<const float4*>(x + ((size_t)b * Nn + n) * FINc);
        #pragma unroll
        for (int i = 0; i < FINc / 4; ++i) {
            float4 v = xp[i];
            xr[4*i+0] = v.x; xr[4*i+1] = v.y; xr[4*i+2] = v.z; xr[4*i+3] = v.w;
        }
        float h1v[H1c];
        #pragma unroll
        for (int h = 0; h < H1c; ++h) {
            float a = b1[h];
            #pragma unroll
            for (int f = 0; f < FINc; ++f) a = fmaf(W1[h*FINc + f], xr[f], a);
            h1v[h] = fmaxf(a, 0.0f);
        }
        #pragma unroll
        for (int g = 0; g < Gc; ++g) {
            float a = b2[g];
            #pragma unroll
            for (int h = 0; h < H1c; ++h) a = fmaf(W2[g*H1c + h], h1v[h], a);
            zA[n][g] = fmaxf(a, 0.0f);
        }
    }
    __syncthreads();

    // ---------------- S passes: z_k = z_{k-1} @ S ----------------
    float z1r[Gc], z2r[Gc];

    auto spass = [&](const float (*zsrc)[Gc], float* zred) {
        float acc[Gc][4];
        #pragma unroll
        for (int g = 0; g < Gc; ++g)
            #pragma unroll
            for (int j = 0; j < 4; ++j) acc[g][j] = 0.0f;

        const float* sbase = S + ((size_t)b * Nn + wid * 32) * Nn + 4 * lane;

        // Ping-pong prefetch: chunks of 4 rows; two named register sets; all
        // indices compile-time after full unroll (no scratch spill, no copies).
        float4 bufA[4], bufB[4];
        #pragma unroll
        for (int i = 0; i < 4; ++i)
            bufA[i] = *reinterpret_cast<const float4*>(sbase + (size_t)i * Nn);

        #pragma unroll
        for (int c = 0; c < 8; ++c) {
            float4* cur = (c & 1) ? bufB : bufA;   // compile-time after unroll
            float4* nxt = (c & 1) ? bufA : bufB;
            if (c < 7) {
                #pragma unroll
                for (int i = 0; i < 4; ++i)
                    nxt[i] = *reinterpret_cast<const float4*>(sbase + (size_t)((c + 1) * 4 + i) * Nn);
            }
            #pragma unroll
            for (int i = 0; i < 4; ++i) {
                const int nn = wid * 32 + c * 4 + i;
                const float4 za = *reinterpret_cast<const float4*>(&zsrc[nn][0]); // b128 broadcast
                const float4 zb = *reinterpret_cast<const float4*>(&zsrc[nn][4]); // b128 broadcast
                const float zg[Gc] = {za.x, za.y, za.z, za.w, zb.x, zb.y, zb.z, zb.w};
                const float4 sv = cur[i];
                #pragma unroll
                for (int g = 0; g < Gc; ++g) {
                    acc[g][0] = fmaf(zg[g], sv.x, acc[g][0]);
                    acc[g][1] = fmaf(zg[g], sv.y, acc[g][1]);
                    acc[g][2] = fmaf(zg[g], sv.z, acc[g][2]);
                    acc[g][3] = fmaf(zg[g], sv.w, acc[g][3]);
                }
            }
        }

        // Two-phase merge: waves 0-3 write, waves 4-7 accumulate on top.
        if (wid < 4) {
            #pragma unroll
            for (int g = 0; g < Gc; ++g)
                *reinterpret_cast<float4*>(&zpart[wid][g][4 * lane]) =
                    make_float4(acc[g][0], acc[g][1], acc[g][2], acc[g][3]);
        }
        __syncthreads();
        if (wid >= 4) {
            #pragma unroll
            for (int g = 0; g < Gc; ++g) {
                float4 cur4 = *reinterpret_cast<const float4*>(&zpart[wid - 4][g][4 * lane]);
                cur4.x += acc[g][0]; cur4.y += acc[g][1]; cur4.z += acc[g][2]; cur4.w += acc[g][3];
                *reinterpret_cast<float4*>(&zpart[wid - 4][g][4 * lane]) = cur4;
            }
        }
        __syncthreads();
        if (tid < Nn) {
            #pragma unroll
            for (int g = 0; g < Gc; ++g)   // stride-1 b32 reads, conflict-free
                zred[g] = (zpart[0][g][n] + zpart[1][g][n]) + (zpart[2][g][n] + zpart[3][g][n]);
        }
    };

    spass(zA, z1r);
    if (tid < Nn) {
        #pragma unroll
        for (int g = 0; g < Gc; ++g) zB[n][g] = z1r[g];    // publish z1 for pass 2
    }
    __syncthreads();                                        // guards zB publish + zpart reuse
    spass(zB, z2r);

    // ---------------- Phase C: graph filter + action head (tid<256) ----------------
    if (tid < Nn) {
        const float4 a0 = *reinterpret_cast<const float4*>(&zA[n][0]);
        const float4 a1 = *reinterpret_cast<const float4*>(&zA[n][4]);
        const float4 b0 = *reinterpret_cast<const float4*>(&zB[n][0]);
        const float4 b1v= *reinterpret_cast<const float4*>(&zB[n][4]);
        const float z0g[Gc] = {a0.x, a0.y, a0.z, a0.w, a1.x, a1.y, a1.z, a1.w};
        const float z1g[Gc] = {b0.x, b0.y, b0.z, b0.w, b1v.x, b1v.y, b1v.z, b1v.w};

        float y[FOUTc];
        #pragma unroll
        for (int f = 0; f < FOUTc; ++f) y[f] = bgf[f];
        #pragma unroll
        for (int g = 0; g < Gc; ++g) {
            #pragma unroll
            for (int f = 0; f < FOUTc; ++f) y[f] = fmaf(Hgf[f*(Kc*Gc) + 0*Gc + g], z0g[g], y[f]);
        }
        #pragma unroll
        for (int g = 0; g < Gc; ++g) {
            #pragma unroll
            for (int f = 0; f < FOUTc; ++f) y[f] = fmaf(Hgf[f*(Kc*Gc) + 1*Gc + g], z1g[g], y[f]);
        }
        #pragma unroll
        for (int g = 0; g < Gc; ++g) {
            #pragma unroll
            for (int f = 0; f < FOUTc; ++f) y[f] = fmaf(Hgf[f*(Kc*Gc) + 2*Gc + g], z2r[g], y[f]);
        }
        #pragma unroll
        for (int f = 0; f < FOUTc; ++f) y[f] = fmaxf(y[f], 0.0f);

        float* op = out + ((size_t)b * Nn + n) * ACTc;
        #pragma unroll
        for (int a = 0; a < ACTc; ++a) {
            float acc = ba[a];
            #pragma unroll
            for (int f = 0; f < FOUTc; ++f) acc = fmaf(Wa[a*FOUTc + f], y[f], acc);
            op[a] = acc;
        }
    }
}

extern "C" void kernel_launch(void* const* d_in, const int* in_sizes, int n_in,
                              void* d_out, int out_size, void* d_ws, size_t ws_size,
                              hipStream_t stream) {
    const float* x   = (const float*)d_in[0];
    const float* S   = (const float*)d_in[1];
    const float* W1  = (const float*)d_in[2];
    const float* b1  = (const float*)d_in[3];
    const float* W2  = (const float*)d_in[4];
    const float* b2  = (const float*)d_in[5];
    const float* Hgf = (const float*)d_in[6];
    const float* bgf = (const float*)d_in[7];
    const float* Wa  = (const float*)d_in[8];
    const float* ba  = (const float*)d_in[9];

    cpn_kernel<<<dim3(Bsz), dim3(512), 0, stream>>>(
        x, S, W1, b1, W2, b2, Hgf, bgf, Wa, ba, (float*)d_out);
}

// Round 6
// 57.252 us; speedup vs baseline: 1.0417x; 1.0417x over previous
//
#include <hip/hip_runtime.h>

// Problem constants (fixed by the reference)
constexpr int Bsz  = 512;
constexpr int Nn   = 256;   // agents
constexpr int FINc = 32;
constexpr int H1c  = 16;
constexpr int Gc   = 8;
constexpr int FOUTc= 16;
constexpr int Kc   = 3;
constexpr int ACTc = 5;

// 256 blocks x 512 threads; block handles batches b and b+256, software-pipelined
// so pass1(b+256) [HBM] overlaps pass2(b) [L3] in different waves of the block.
// Every S-pass is a 4-wave pass: wave-in-group owns 64 rows, lane owns 4 cols (float4).
__global__ __launch_bounds__(512, 2)
void cpn_kernel(const float* __restrict__ x,  const float* __restrict__ S,
                const float* __restrict__ W1, const float* __restrict__ b1,
                const float* __restrict__ W2, const float* __restrict__ b2,
                const float* __restrict__ Hgf,const float* __restrict__ bgf,
                const float* __restrict__ Wa, const float* __restrict__ ba,
                float* __restrict__ out)
{
    const int blk  = blockIdx.x;     // 0..255
    const int bb0  = blk;            // first batch
    const int bb1  = blk + 256;      // second batch
    const int tid  = threadIdx.x;
    const int wid  = tid >> 6;
    const int lane = tid & 63;

    __shared__ __align__(16) float zA0[Nn][Gc], zA1[Nn][Gc];       // z0 per batch (8 KB each)
    __shared__ __align__(16) float zB0[Nn][Gc], zB1[Nn][Gc];       // z1 per batch
    __shared__ __align__(16) float zpA[4][Gc][Nn], zpB[4][Gc][Nn]; // partials (32 KB each)

    // ---------------- S0: compress MLP for BOTH batches (thread -> (sel, n)) ------------
    {
        const int sel = tid >> 8;          // 0 or 1
        const int n   = tid & 255;
        const int bb  = sel ? bb1 : bb0;
        float (*zdst)[Gc] = sel ? zA1 : zA0;

        float xr[FINc];
        const float4* xp = reinterpret_cast<const float4*>(x + ((size_t)bb * Nn + n) * FINc);
        #pragma unroll
        for (int i = 0; i < FINc / 4; ++i) {
            float4 v = xp[i];
            xr[4*i+0] = v.x; xr[4*i+1] = v.y; xr[4*i+2] = v.z; xr[4*i+3] = v.w;
        }
        float h1v[H1c];
        #pragma unroll
        for (int h = 0; h < H1c; ++h) {
            float a = b1[h];
            #pragma unroll
            for (int f = 0; f < FINc; ++f) a = fmaf(W1[h*FINc + f], xr[f], a);
            h1v[h] = fmaxf(a, 0.0f);
        }
        #pragma unroll
        for (int g = 0; g < Gc; ++g) {
            float a = b2[g];
            #pragma unroll
            for (int h = 0; h < H1c; ++h) a = fmaf(W2[g*H1c + h], h1v[h], a);
            zdst[n][g] = fmaxf(a, 0.0f);
        }
    }
    __syncthreads();

    // 4-wave S-pass: rows 64*wg4 .. +63, lane cols 4*lane..+3; flat loop (no manual pipelining)
    auto spass4 = [&](const float (*zsrc)[Gc], float (*zp)[Gc][Nn],
                      const float* sbatch, int wg4) {
        float acc[Gc][4];
        #pragma unroll
        for (int g = 0; g < Gc; ++g)
            #pragma unroll
            for (int j = 0; j < 4; ++j) acc[g][j] = 0.0f;

        const float* srow = sbatch + (size_t)(wg4 * 64) * Nn + 4 * lane;
        #pragma unroll 8
        for (int i = 0; i < 64; ++i) {
            const float4 sv = *reinterpret_cast<const float4*>(srow);  // coalesced 16B/lane
            srow += Nn;
            const int nn = wg4 * 64 + i;
            const float4 za = *reinterpret_cast<const float4*>(&zsrc[nn][0]); // b128 broadcast
            const float4 zb = *reinterpret_cast<const float4*>(&zsrc[nn][4]);
            const float zg[Gc] = {za.x, za.y, za.z, za.w, zb.x, zb.y, zb.z, zb.w};
            #pragma unroll
            for (int g = 0; g < Gc; ++g) {
                acc[g][0] = fmaf(zg[g], sv.x, acc[g][0]);
                acc[g][1] = fmaf(zg[g], sv.y, acc[g][1]);
                acc[g][2] = fmaf(zg[g], sv.z, acc[g][2]);
                acc[g][3] = fmaf(zg[g], sv.w, acc[g][3]);
            }
        }
        #pragma unroll
        for (int g = 0; g < Gc; ++g)
            *reinterpret_cast<float4*>(&zp[wg4][g][4 * lane]) =
                make_float4(acc[g][0], acc[g][1], acc[g][2], acc[g][3]);
    };

    auto merge_pub = [&](const float (*zp)[Gc][Nn], float (*zdst)[Gc], int n) {
        #pragma unroll
        for (int g = 0; g < Gc; ++g)
            zdst[n][g] = (zp[0][g][n] + zp[1][g][n]) + (zp[2][g][n] + zp[3][g][n]);
    };
    auto merge_reg = [&](const float (*zp)[Gc][Nn], float* zr, int n) {
        #pragma unroll
        for (int g = 0; g < Gc; ++g)
            zr[g] = (zp[0][g][n] + zp[1][g][n]) + (zp[2][g][n] + zp[3][g][n]);
    };
    auto phaseC = [&](int bb, int n, const float (*z0s)[Gc], const float (*z1s)[Gc],
                      const float* z2r) {
        const float4 a0 = *reinterpret_cast<const float4*>(&z0s[n][0]);
        const float4 a1 = *reinterpret_cast<const float4*>(&z0s[n][4]);
        const float4 c0 = *reinterpret_cast<const float4*>(&z1s[n][0]);
        const float4 c1 = *reinterpret_cast<const float4*>(&z1s[n][4]);
        const float z0g[Gc] = {a0.x, a0.y, a0.z, a0.w, a1.x, a1.y, a1.z, a1.w};
        const float z1g[Gc] = {c0.x, c0.y, c0.z, c0.w, c1.x, c1.y, c1.z, c1.w};

        float y[FOUTc];
        #pragma unroll
        for (int f = 0; f < FOUTc; ++f) y[f] = bgf[f];
        #pragma unroll
        for (int g = 0; g < Gc; ++g) {
            #pragma unroll
            for (int f = 0; f < FOUTc; ++f) y[f] = fmaf(Hgf[f*(Kc*Gc) + 0*Gc + g], z0g[g], y[f]);
        }
        #pragma unroll
        for (int g = 0; g < Gc; ++g) {
            #pragma unroll
            for (int f = 0; f < FOUTc; ++f) y[f] = fmaf(Hgf[f*(Kc*Gc) + 1*Gc + g], z1g[g], y[f]);
        }
        #pragma unroll
        for (int g = 0; g < Gc; ++g) {
            #pragma unroll
            for (int f = 0; f < FOUTc; ++f) y[f] = fmaf(Hgf[f*(Kc*Gc) + 2*Gc + g], z2r[g], y[f]);
        }
        #pragma unroll
        for (int f = 0; f < FOUTc; ++f) y[f] = fmaxf(y[f], 0.0f);

        float* op = out + ((size_t)bb * Nn + n) * ACTc;
        #pragma unroll
        for (int a = 0; a < ACTc; ++a) {
            float acc = ba[a];
            #pragma unroll
            for (int f = 0; f < FOUTc; ++f) acc = fmaf(Wa[a*FOUTc + f], y[f], acc);
            op[a] = acc;
        }
    };

    const float* S0p = S + (size_t)bb0 * Nn * Nn;
    const float* S1p = S + (size_t)bb1 * Nn * Nn;

    // ---- S1: pass1(b0) by waves 0-3 [HBM] ----
    if (wid < 4) spass4(zA0, zpA, S0p, wid);
    __syncthreads();
    if (tid < Nn) merge_pub(zpA, zB0, tid);            // z1(b0) -> zB0
    __syncthreads();

    // ---- S2: pass1(b1) [HBM, w0-3]  ||  pass2(b0) [L3, w4-7] ----
    if (wid < 4) spass4(zA1, zpB, S1p, wid);
    else         spass4(zB0, zpA, S0p, wid - 4);
    __syncthreads();
    if (tid < Nn) {
        merge_pub(zpB, zB1, tid);                      // z1(b1) -> zB1
    } else {
        const int n = tid - Nn;
        float z2r[Gc];
        merge_reg(zpA, z2r, n);                        // z2(b0)
        phaseC(bb0, n, zA0, zB0, z2r);                 // finish batch b0
    }
    __syncthreads();

    // ---- S3: pass2(b1) [L3] by waves 0-3 ----
    if (wid < 4) spass4(zB1, zpB, S1p, wid);
    __syncthreads();
    if (tid < Nn) {
        float z2r[Gc];
        merge_reg(zpB, z2r, tid);                      // z2(b1)
        phaseC(bb1, tid, zA1, zB1, z2r);               // finish batch b1
    }
}

extern "C" void kernel_launch(void* const* d_in, const int* in_sizes, int n_in,
                              void* d_out, int out_size, void* d_ws, size_t ws_size,
                              hipStream_t stream) {
    const float* x   = (const float*)d_in[0];
    const float* S   = (const float*)d_in[1];
    const float* W1  = (const float*)d_in[2];
    const float* b1  = (const float*)d_in[3];
    const float* W2  = (const float*)d_in[4];
    const float* b2  = (const float*)d_in[5];
    const float* Hgf = (const float*)d_in[6];
    const float* bgf = (const float*)d_in[7];
    const float* Wa  = (const float*)d_in[8];
    const float* ba  = (const float*)d_in[9];

    cpn_kernel<<<dim3(Bsz / 2), dim3(512), 0, stream>>>(
        x, S, W1, b1, W2, b2, Hgf, bgf, Wa, ba, (float*)d_out);
}